// Round 7
// baseline (104.791 us; speedup 1.0000x reference)
//
#include <hip/hip_runtime.h>

typedef __attribute__((ext_vector_type(8))) short short8;
typedef __attribute__((ext_vector_type(4))) short short4v;
typedef __attribute__((ext_vector_type(8))) signed char s8x8;
typedef __attribute__((ext_vector_type(4))) unsigned char u8x4;
typedef __attribute__((ext_vector_type(4))) float f32x4;
typedef __attribute__((ext_vector_type(4))) int int4v;
typedef __attribute__((ext_vector_type(4))) unsigned int u32x4;

#define THRE 4.0f

#define GLOAD_LDS16(g, l) \
    __builtin_amdgcn_global_load_lds((const __attribute__((address_space(1))) void*)(g), \
                                     (__attribute__((address_space(3))) void*)(l), 16, 0, 0)
#define WAIT_VM(n)  asm volatile("s_waitcnt vmcnt(" #n ")" ::: "memory")
#define WAIT_LGKM0  asm volatile("s_waitcnt lgkmcnt(0)" ::: "memory")
#define SBAR        __builtin_amdgcn_s_barrier()
#define SCHEDBAR    __builtin_amdgcn_sched_barrier(0)

__device__ __forceinline__ float spikef(float x) {
    return floorf(fminf(fmaxf(x, 0.0f), THRE) + 0.5f);
}
__device__ __forceinline__ unsigned short f2bf(float f) {   // truncate; exact for small ints
    return (unsigned short)(__builtin_bit_cast(unsigned int, f) >> 16);
}
__device__ __forceinline__ unsigned short f2bf_rn(float f) { // round-to-nearest
    unsigned u = __builtin_bit_cast(unsigned int, f);
    unsigned r = ((u >> 16) & 1u) + 0x7FFFu;
    return (unsigned short)((u + r) >> 16);
}
__device__ __forceinline__ float bf2f(unsigned short s) {
    return __builtin_bit_cast(float, (unsigned int)s << 16);
}
__device__ __forceinline__ int4v mfma_i8(u32x4 a, u32x4 b, int4v c) {
    return __builtin_amdgcn_mfma_i32_16x16x64_i8(__builtin_bit_cast(int4v, a),
                                                 __builtin_bit_cast(int4v, b), c, 0, 0, 0);
}

// ---------- prep: x -> i8 spike; Wqkv -> i8 per-row quant + scale ----------
__global__ void k_prep(const float* __restrict__ x, const float* __restrict__ Wq,
                       unsigned char* __restrict__ xs8, signed char* __restrict__ Wq8,
                       float* __restrict__ wscale) {
    const int blk = blockIdx.x, tid = threadIdx.x;
    if (blk < 2048) {                                    // x: 2097152 floats, 4/thread
        const int i = blk * 256 + tid;
        const float4 v = *(const float4*)&x[(size_t)i * 4];
        u8x4 o;
        o.x = (unsigned char)spikef(v.x);
        o.y = (unsigned char)spikef(v.y);
        o.z = (unsigned char)spikef(v.z);
        o.w = (unsigned char)spikef(v.w);
        *(u8x4*)&xs8[(size_t)i * 4] = o;
    } else {                                             // Wqkv: 1536 rows of 512
        const int row = (blk - 2048) * 4 + (tid >> 6);
        const int lane = tid & 63;
        const float* wr = Wq + (size_t)row * 512 + lane * 8;
        float w[8];
        float mx = 0.f;
        #pragma unroll
        for (int i = 0; i < 8; ++i) { w[i] = wr[i]; mx = fmaxf(mx, fabsf(w[i])); }
        #pragma unroll
        for (int o = 32; o > 0; o >>= 1) mx = fmaxf(mx, __shfl_xor(mx, o, 64));
        const float inv = mx > 0.f ? 127.0f / mx : 0.f;
        s8x8 q;
        #pragma unroll
        for (int i = 0; i < 8; ++i) q[i] = (signed char)rintf(w[i] * inv);
        *(s8x8*)&Wq8[(size_t)row * 512 + lane * 8] = q;
        if (lane == 0) wscale[row] = mx > 0.f ? mx / 127.0f : 0.f;
    }
}

// ---------- qkv GEMM (i8): M=4096 N=1536 K=512, dbuf LDS + counted vmcnt ----------
__global__ __launch_bounds__(256) void k_gemm_qkv(const unsigned char* __restrict__ A,
                                                  const signed char* __restrict__ B,
                                                  const float* __restrict__ wscale,
                                                  short* __restrict__ C,
                                                  float* __restrict__ psum,
                                                  float* __restrict__ psq) {
    __shared__ __align__(16) unsigned char As[2][128 * 128];  // 32 KB
    __shared__ __align__(16) unsigned char Bs[2][96 * 128];   // 24 KB
    const int tid  = threadIdx.x;
    const int lane = tid & 63, wv = tid >> 6;
    const int wy = wv >> 1, wx = wv & 1;
    const int quad = lane >> 4, l16 = lane & 15;
    const int u = blockIdx.x;
    const int mtile = u & 31;                      // XCD = u%8
    const int m0 = mtile * 128, n0 = (u >> 5) * 96;
    const int N = 1536;

    // anchor scale loads NOW so the k-loop's vmcnt ledger contains only glds ops
    float sc[3];
    #pragma unroll
    for (int nt = 0; nt < 3; ++nt) sc[nt] = wscale[n0 + wx * 48 + nt * 16 + l16];
    asm volatile("" :: "v"(sc[0]), "v"(sc[1]), "v"(sc[2]));

    int4v acc[4][3];
    #pragma unroll
    for (int i = 0; i < 4; ++i)
        #pragma unroll
        for (int j = 0; j < 3; ++j)
            #pragma unroll
            for (int r = 0; r < 4; ++r) acc[i][j][r] = 0;

    const unsigned char* gA[4]; int lA[4];
    #pragma unroll
    for (int i = 0; i < 4; ++i) {
        int c = (wv + 4 * i) * 64 + lane;
        int r = c >> 3, g = (c & 7) ^ (r & 7);
        gA[i] = A + (size_t)(m0 + r) * 512 + g * 16;
        lA[i] = c * 16;
    }
    const unsigned char* gB[3]; int lB[3];
    #pragma unroll
    for (int i = 0; i < 3; ++i) {
        int c = (wv + 4 * i) * 64 + lane;
        int r = c >> 3, g = (c & 7) ^ (r & 7);
        gB[i] = (const unsigned char*)B + (size_t)(n0 + r) * 512 + g * 16;
        lB[i] = c * 16;
    }

    // prologue: stage tile 0 -> buf 0
    #pragma unroll
    for (int i = 0; i < 4; ++i) GLOAD_LDS16(gA[i], &As[0][lA[i]]);
    #pragma unroll
    for (int i = 0; i < 3; ++i) GLOAD_LDS16(gB[i], &Bs[0][lB[i]]);

    for (int t = 0; t < 4; ++t) {
        if (t > 0) {           // WAR: all waves done computing t-1 before overwriting its buffer
            WAIT_LGKM0;
            SBAR;
        }
        if (t < 3) {           // stage t+1 -> other buffer; flies under this tile's compute
            const int k0n = (t + 1) * 128;
            const int bn = (t + 1) & 1;
            #pragma unroll
            for (int i = 0; i < 4; ++i) GLOAD_LDS16(gA[i] + k0n, &As[bn][lA[i]]);
            #pragma unroll
            for (int i = 0; i < 3; ++i) GLOAD_LDS16(gB[i] + k0n, &Bs[bn][lB[i]]);
            WAIT_VM(7);        // tile-t loads (issued one phase ago) complete
        } else {
            WAIT_VM(0);
        }
        SBAR;
        SCHEDBAR;
        const int bc = t & 1;
        #pragma unroll
        for (int kk = 0; kk < 2; ++kk) {
            u32x4 aF[4], bF[3];
            #pragma unroll
            for (int mt = 0; mt < 4; ++mt) {
                const int r = wy * 64 + mt * 16 + l16;
                aF[mt] = *(const u32x4*)&As[bc][(size_t)r * 128 + (((kk * 4 + quad) ^ (r & 7)) * 16)];
            }
            #pragma unroll
            for (int nt = 0; nt < 3; ++nt) {
                const int r = wx * 48 + nt * 16 + l16;
                bF[nt] = *(const u32x4*)&Bs[bc][(size_t)r * 128 + (((kk * 4 + quad) ^ (r & 7)) * 16)];
            }
            #pragma unroll
            for (int mt = 0; mt < 4; ++mt)
                #pragma unroll
                for (int nt = 0; nt < 3; ++nt)
                    acc[mt][nt] = mfma_i8(aF[mt], bF[nt], acc[mt][nt]);
        }
    }

    float vacc[4][3][4];
    #pragma unroll
    for (int mt = 0; mt < 4; ++mt)
        #pragma unroll
        for (int r = 0; r < 4; ++r) {
            int row = m0 + wy * 64 + mt * 16 + quad * 4 + r;
            short* Cr = C + (size_t)row * N + n0 + wx * 48 + l16;
            #pragma unroll
            for (int nt = 0; nt < 3; ++nt) {
                float v = (float)acc[mt][nt][r] * sc[nt];
                vacc[mt][nt][r] = v;
                Cr[nt * 16] = (short)f2bf_rn(v);
            }
        }

    __syncthreads();
    float* PS = (float*)&As[0][0];   // [8][96]
    float* PQ = (float*)&As[1][0];
    #pragma unroll
    for (int nt = 0; nt < 3; ++nt) {
        float s = 0.f, q = 0.f;
        #pragma unroll
        for (int mt = 0; mt < 4; ++mt)
            #pragma unroll
            for (int r = 0; r < 4; ++r) {
                float v = vacc[mt][nt][r];
                s += v;
                q = fmaf(v, v, q);
            }
        PS[(wy * 4 + quad) * 96 + wx * 48 + nt * 16 + l16] = s;
        PQ[(wy * 4 + quad) * 96 + wx * 48 + nt * 16 + l16] = q;
    }
    __syncthreads();
    if (tid < 96) {
        float s = 0.f, q = 0.f;
        #pragma unroll
        for (int i = 0; i < 8; ++i) { s += PS[i * 96 + tid]; q += PQ[i * 96 + tid]; }
        psum[mtile * 1536 + n0 + tid] = s;
        psq [mtile * 1536 + n0 + tid] = q;
    }
}

// ---------- BN finalize + spike + pack (vectorized, v-path dbuf) + Wproj->bf16 rider ----------
// vt layout: [bh][t=j/256][kk=(j/64)%4][d=0..63][quad=(j/16)%4][16B j-bytes]
__global__ __launch_bounds__(256) void k_bn_spike(const short* __restrict__ qkvb,
                           const float* __restrict__ psum, const float* __restrict__ psq,
                           const float* __restrict__ gamma, const float* __restrict__ beta,
                           unsigned char* __restrict__ qp, unsigned char* __restrict__ kp,
                           unsigned char* __restrict__ vt,
                           const float* __restrict__ Wp, short* __restrict__ Wpd) {
    __shared__ float sa[64], sb[64];
    __shared__ __align__(16) unsigned char tile[2][64 * 80];
    const int tid = threadIdx.x;
    const int slice = blockIdx.x;            // 0..23
    const int c0 = slice * 64;
    const int r0 = blockIdx.y * 256;
    const int b = r0 >> 10, nb = r0 & 1023;

    // Wproj -> bf16 rider: 262144 floats over first 65536 threads, 4 each, coalesced
    {
        const int gid = (blockIdx.y * 24 + blockIdx.x) * 256 + tid;
        if (gid < 65536) {
            const float4 v = *(const float4*)&Wp[(size_t)gid * 4];
            short4v o;
            o.x = (short)f2bf_rn(v.x);
            o.y = (short)f2bf_rn(v.y);
            o.z = (short)f2bf_rn(v.z);
            o.w = (short)f2bf_rn(v.w);
            *(short4v*)&Wpd[(size_t)gid * 4] = o;
        }
    }

    if (tid < 64) {
        const int c = c0 + tid;
        double s = 0.0, q = 0.0;
        for (int st = 0; st < 32; ++st) { s += (double)psum[st * 1536 + c]; q += (double)psq[st * 1536 + c]; }
        const double mu  = s / 4096.0;
        const double var = q / 4096.0 - mu * mu;
        const float a = (float)((double)gamma[c] / sqrt(var + 1e-5));
        sa[tid] = a;
        sb[tid] = fmaf(-(float)mu, a, beta[c]);
    }
    __syncthreads();

    const int ch8 = (tid & 7) * 8;
    float A8[8], B8[8];
    #pragma unroll
    for (int j = 0; j < 8; ++j) { A8[j] = sa[ch8 + j]; B8[j] = sb[ch8 + j]; }

    if (slice < 16) {
        const int h = slice & 7;
        const int rr = tid >> 3;                           // 32 rows/pass, 8 passes
        unsigned char* base = (slice < 8 ? qp : kp) + (((size_t)b * 8 + h) * 1024 + nb) * 64;
        for (int i = rr; i < 256; i += 32) {
            const short8 v8 = *(const short8*)&qkvb[(size_t)(r0 + i) * 1536 + c0 + ch8];
            unsigned lo = 0, hi = 0;
            #pragma unroll
            for (int j = 0; j < 4; ++j)
                lo |= (unsigned)(unsigned char)spikef(fmaf(bf2f((unsigned short)v8[j]), A8[j], B8[j])) << (8 * j);
            #pragma unroll
            for (int j = 0; j < 4; ++j)
                hi |= (unsigned)(unsigned char)spikef(fmaf(bf2f((unsigned short)v8[4 + j]), A8[4 + j], B8[4 + j])) << (8 * j);
            uint2 o; o.x = lo; o.y = hi;
            *(uint2*)&base[(size_t)i * 64 + ch8] = o;
        }
    } else {
        const int h = slice - 16;
        const int rw = tid >> 3;                           // 32 rows/pass
        const int e = tid >> 2, j0 = (tid & 3) * 16;
        // fragment-linear target: bh*65536 + (nb>>8)*16384 + rb*4096 + d*64 + j
        unsigned char* vbase = vt + (size_t)b * 524288 + (size_t)h * 65536
                             + (size_t)(nb >> 8) * 16384 + e * 64 + j0;
        #pragma unroll
        for (int rb = 0; rb < 4; ++rb) {
            unsigned char* tb = tile[rb & 1];
            #pragma unroll
            for (int p = 0; p < 2; ++p) {
                const int row = p * 32 + rw;
                const short8 v8 = *(const short8*)&qkvb[(size_t)(r0 + rb * 64 + row) * 1536 + c0 + ch8];
                #pragma unroll
                for (int j = 0; j < 8; ++j)
                    tb[(ch8 + j) * 80 + row] =
                        (unsigned char)spikef(fmaf(bf2f((unsigned short)v8[j]), A8[j], B8[j]));
            }
            __syncthreads();                               // tb ready; prev buffer reads done
            *(u32x4*)&vbase[rb * 4096] = *(const u32x4*)&tb[e * 80 + j0];
        }
    }
}

// ---------- fused i8-MFMA attention: direct-global fragments, K+V register dbuf, dbuf S ----------
__global__ __launch_bounds__(256) void k_attn(const unsigned char* __restrict__ qp,
                                              const unsigned char* __restrict__ kp,
                                              const unsigned char* __restrict__ vt,
                                              short* __restrict__ sout) {
    __shared__ __align__(16) unsigned int Sb[2][64 * 68];   // 34 KB double-buffered S exchange
    const int tid  = threadIdx.x;
    const int lane = tid & 63, w = tid >> 6;
    const int quad = lane >> 4, l16 = lane & 15;
    const int u = blockIdx.x;
    const int bhid = u & 31;                       // XCD = u%8 = bhid%8 -> K/V L2-local
    const int b = bhid >> 3, h = bhid & 7;
    const int n0 = (u >> 5) * 64;
    const size_t bh = (size_t)b * 8 + h;

    const unsigned char* Kb = kp + bh * 65536;     // [n][64]
    const unsigned char* Vb = vt + bh * 65536;     // fragment-linear

    u32x4 qf[4];
    #pragma unroll
    for (int mt = 0; mt < 4; ++mt)
        qf[mt] = *(const u32x4*)&qp[(bh * 1024 + n0 + mt * 16 + l16) * 64 + quad * 16];

    int4v of[4];
    #pragma unroll
    for (int mt = 0; mt < 4; ++mt)
        #pragma unroll
        for (int r = 0; r < 4; ++r) of[mt][r] = 0;

    // register double-buffers for K and V fragments
    u32x4 kfc[2][4], bV[2][4];
    #pragma unroll
    for (int jt = 0; jt < 4; ++jt)
        kfc[0][jt] = *(const u32x4*)&Kb[(size_t)(w * 64 + jt * 16 + l16) * 64 + quad * 16];
    #pragma unroll
    for (int kk = 0; kk < 4; ++kk)
        bV[0][kk] = *(const u32x4*)&Vb[(size_t)(kk * 64 + w * 16 + l16) * 64 + quad * 16];

    #pragma unroll
    for (int t = 0; t < 4; ++t) {
        const int cur = t & 1, nxt = cur ^ 1;
        // issue next tile's K and V fragments NOW; a full tile of compute covers their latency
        if (t < 3) {
            #pragma unroll
            for (int jt = 0; jt < 4; ++jt)
                kfc[nxt][jt] = *(const u32x4*)&Kb[(size_t)((t + 1) * 256 + w * 64 + jt * 16 + l16) * 64 + quad * 16];
            #pragma unroll
            for (int kk = 0; kk < 4; ++kk)
                bV[nxt][kk] = *(const u32x4*)&Vb[(size_t)(((t + 1) * 4 + kk) * 64 + w * 16 + l16) * 64 + quad * 16];
        }

        __builtin_amdgcn_s_setprio(1);
        #pragma unroll
        for (int jt = 0; jt < 4; ++jt) {
            #pragma unroll
            for (int mt = 0; mt < 4; ++mt) {
                int4v z;
                #pragma unroll
                for (int r = 0; r < 4; ++r) z[r] = 0;
                int4v s = mfma_i8(kfc[cur][jt], qf[mt], z);
                unsigned int pkk = 0;
                #pragma unroll
                for (int r = 0; r < 4; ++r) {
                    int v = s[r]; v = v < 0 ? 0 : (v > 4 ? 4 : v);
                    pkk |= (unsigned int)v << (8 * r);
                }
                Sb[cur][(mt * 16 + l16) * 68 + w * 16 + jt * 4 + quad] = pkk;
            }
        }
        __builtin_amdgcn_s_setprio(0);
        __syncthreads();

        __builtin_amdgcn_s_setprio(1);
        #pragma unroll
        for (int kk = 0; kk < 4; ++kk) {
            #pragma unroll
            for (int mt = 0; mt < 4; ++mt) {
                u32x4 aS = *(const u32x4*)&Sb[cur][(mt * 16 + l16) * 68 + kk * 16 + quad * 4];
                of[mt] = mfma_i8(aS, bV[cur][kk], of[mt]);
            }
        }
        __builtin_amdgcn_s_setprio(0);
    }

    #pragma unroll
    for (int mt = 0; mt < 4; ++mt)
        #pragma unroll
        for (int r = 0; r < 4; ++r) {
            size_t orow = (size_t)b * 1024 + n0 + mt * 16 + quad * 4 + r;
            sout[orow * 512 + h * 64 + w * 16 + l16] =
                (short)f2bf(spikef((float)of[mt][r] * 0.125f));
        }
}

// ---------- proj GEMM (bf16): resident A panel + dbuf B, counted vmcnt ----------
__global__ __launch_bounds__(256) void k_gemm_proj(const short* __restrict__ A,
                                                   const short* __restrict__ B,
                                                   const float* __restrict__ bias,
                                                   float* __restrict__ C) {
    __shared__ __align__(16) short As[32 * 512];      // 32 KB resident A panel
    __shared__ __align__(16) short Bs[2][128 * 64];   // 32 KB dbuf B
    const int tid  = threadIdx.x;
    const int lane = tid & 63, wv = tid >> 6;
    const int wy = wv >> 1, wx = wv & 1;
    const int quad = lane >> 4, l16 = lane & 15;
    const int u = blockIdx.x;
    const int mtile = u & 127;                     // XCD = u%8 = mtile%8
    const int m0 = mtile * 32, n0 = (u >> 7) * 128;
    const int N = 512;

    // anchor bias loads so the k-loop vmcnt ledger is glds-only
    float bs[4];
    #pragma unroll
    for (int nt = 0; nt < 4; ++nt) bs[nt] = bias[n0 + wx * 64 + nt * 16 + l16];
    asm volatile("" :: "v"(bs[0]), "v"(bs[1]), "v"(bs[2]), "v"(bs[3]));

    f32x4 acc[4];
    #pragma unroll
    for (int j = 0; j < 4; ++j)
        #pragma unroll
        for (int r = 0; r < 4; ++r) acc[j][r] = 0.f;

    // A: 2048 granules (32 rows x 64), 8/thread; slot s8 of block kb holds global granule s8^(r&7)
    const short* gAg[8]; int lAo[8];
    #pragma unroll
    for (int i = 0; i < 8; ++i) {
        int c = tid + 256 * i;
        int r = c >> 6, slot = c & 63, kb = slot >> 3, s8 = slot & 7;
        gAg[i] = A + (size_t)(m0 + r) * 512 + (kb * 8 + (s8 ^ (r & 7))) * 8;
        lAo[i] = c * 8;
    }
    // B: 1024 granules/tile (128 rows x 8), 4/thread
    const short* gBg[4]; int lBo[4];
    #pragma unroll
    for (int i = 0; i < 4; ++i) {
        int c = tid + 256 * i;
        int r = c >> 3, s8 = c & 7;
        gBg[i] = B + (size_t)(n0 + r) * 512 + (s8 ^ (r & 7)) * 8;
        lBo[i] = c * 8;
    }

    // prologue: resident A + B tile 0
    #pragma unroll
    for (int i = 0; i < 8; ++i) GLOAD_LDS16(gAg[i], &As[lAo[i]]);
    #pragma unroll
    for (int i = 0; i < 4; ++i) GLOAD_LDS16(gBg[i], &Bs[0][lBo[i]]);

    for (int t = 0; t < 8; ++t) {
        if (t > 0) {           // WAR before overwriting the buffer tile t-1 used
            WAIT_LGKM0;
            SBAR;
        }
        if (t < 7) {
            const int bn = (t + 1) & 1;
            #pragma unroll
            for (int i = 0; i < 4; ++i) GLOAD_LDS16(gBg[i] + (t + 1) * 64, &Bs[bn][lBo[i]]);
            WAIT_VM(4);
        } else {
            WAIT_VM(0);
        }
        SBAR;
        SCHEDBAR;
        const int bc = t & 1;
        #pragma unroll
        for (int kk = 0; kk < 2; ++kk) {
            const int ra = wy * 16 + l16;
            short8 aF = *(const short8*)&As[(size_t)ra * 512 + t * 64 + (((kk * 4 + quad) ^ (ra & 7)) * 8)];
            #pragma unroll
            for (int nt = 0; nt < 4; ++nt) {
                const int rb = wx * 64 + nt * 16 + l16;
                short8 bF = *(const short8*)&Bs[bc][(size_t)rb * 64 + (((kk * 4 + quad) ^ (rb & 7)) * 8)];
                acc[nt] = __builtin_amdgcn_mfma_f32_16x16x32_bf16(aF, bF, acc[nt], 0, 0, 0);
            }
        }
    }

    #pragma unroll
    for (int r = 0; r < 4; ++r) {
        int row = m0 + wy * 16 + quad * 4 + r;
        float* Cr = C + (size_t)row * N + n0 + wx * 64 + l16;
        #pragma unroll
        for (int nt = 0; nt < 4; ++nt) Cr[nt * 16] = acc[nt][r] + bs[nt];
    }
}

extern "C" void kernel_launch(void* const* d_in, const int* in_sizes, int n_in,
                              void* d_out, int out_size, void* d_ws, size_t ws_size,
                              hipStream_t stream) {
    const float* x     = (const float*)d_in[0];
    const float* Wqkv  = (const float*)d_in[1];
    const float* gamma = (const float*)d_in[2];
    const float* beta  = (const float*)d_in[3];
    const float* Wproj = (const float*)d_in[4];
    const float* bproj = (const float*)d_in[5];
    float* out = (float*)d_out;

    char* w = (char*)d_ws;
    unsigned char* xs8   = (unsigned char*)(w);             // 2 MB; region reused as sout (4 MB)
    signed char* Wq8     = (signed char*)(w + 8388608);     // 0.75 MB
    float* wscale        = (float*)(w + 9437184);           // 6 KB
    short* Wpd           = (short*)(w + 11534336);          // 0.5 MB
    short* qkvb          = (short*)(w + 12582912);          // 12 MB (bf16)
    unsigned char* qp    = (unsigned char*)(w + 37748736);  // 2 MB
    unsigned char* kp    = (unsigned char*)(w + 41943040);  // 2 MB
    unsigned char* vt    = (unsigned char*)(w + 46137344);  // 2 MB
    float* psum          = (float*)(w + 50331648);
    float* psq           = psum + 32 * 1536;
    short* sout          = (short*)(w);                     // xs8 dead after qkv GEMM

    k_prep     <<<2432, 256, 0, stream>>>(x, Wqkv, xs8, Wq8, wscale);
    k_gemm_qkv <<<512, 256, 0, stream>>>(xs8, Wq8, wscale, qkvb, psum, psq);
    k_bn_spike <<<dim3(24, 16), 256, 0, stream>>>(qkvb, psum, psq, gamma, beta, qp, kp, vt, Wproj, Wpd);
    k_attn     <<<512, 256, 0, stream>>>(qp, kp, vt, sout);
    k_gemm_proj<<<512, 256, 0, stream>>>(sout, Wpd, bproj, out);
}